// Round 1
// baseline (51.923 us; speedup 1.0000x reference)
//
#include <hip/hip_runtime.h>
#include <math.h>

#define TB 256
#define PI_F 3.14159265358979323846f

__device__ __forceinline__ float fast_tanh(float p) {
    // tanh(p) = 1 - 2/(exp(2p)+1); __expf -> v_exp_f32, __fdividef -> v_rcp_f32
    float t = __expf(2.0f * p);
    return 1.0f - __fdividef(2.0f, t + 1.0f);
}

__global__ __launch_bounds__(TB) void sqru_fused_kernel(
    const float* __restrict__ x, const float* __restrict__ Wp,
    const float* __restrict__ bp, const float* __restrict__ qw,
    const float* __restrict__ W1, const float* __restrict__ b1,
    const float* __restrict__ W2, const float* __restrict__ b2,
    float* __restrict__ out, int nrows)
{
    __shared__ float wp_s[16 * 256];   // 16 KB
    __shared__ float w1_s[32 * 8];
    __shared__ float w2_s[10 * 32];
    __shared__ float b1_s[32];
    __shared__ float b2_s[10];
    __shared__ float bp_s[16];
    __shared__ float rot_s[8][3][6];   // per (unit,layer): cos/sin(qw0), cos/sin(qw1/2), cos/sin(qw2)
    __shared__ float out_s[TB * 10];

    const int t = threadIdx.x;

    // ---- stage weights to LDS (coalesced) ----
    {
        const float4* src = (const float4*)Wp;
        float4* dst = (float4*)wp_s;
        #pragma unroll
        for (int i = 0; i < 4; ++i) dst[t + i * TB] = src[t + i * TB];
    }
    if (t < 64) ((float4*)w1_s)[t] = ((const float4*)W1)[t];
    if (t < 80) ((float4*)w2_s)[t] = ((const float4*)W2)[t];
    if (t < 32) b1_s[t] = b1[t];
    if (t < 10) b2_s[t] = b2[t];
    if (t < 16) bp_s[t] = bp[t];
    if (t < 24) {
        int u = t / 3, l = t % 3;
        float q0 = qw[u * 9 + l * 3 + 0];
        float q1 = qw[u * 9 + l * 3 + 1];
        float q2 = qw[u * 9 + l * 3 + 2];
        rot_s[u][l][0] = cosf(q0);        rot_s[u][l][1] = sinf(q0);
        rot_s[u][l][2] = cosf(0.5f * q1); rot_s[u][l][3] = sinf(0.5f * q1);
        rot_s[u][l][4] = cosf(q2);        rot_s[u][l][5] = sinf(q2);
    }
    __syncthreads();

    int row = blockIdx.x * TB + t;
    if (row >= nrows) row = nrows - 1;   // exact fit for B=131072; safety clamp

    // ---- projection GEMV: acc[16] = x_row . Wp^T + bp ----
    float acc[16];
    #pragma unroll
    for (int j = 0; j < 16; ++j) acc[j] = bp_s[j];

    const float4* xr = (const float4*)(x + (size_t)row * 256);
    #pragma unroll 8
    for (int d = 0; d < 64; ++d) {
        float4 xv = xr[d];
        #pragma unroll
        for (int j = 0; j < 16; ++j) {
            float4 w = ((const float4*)wp_s)[j * 64 + d];  // broadcast read
            acc[j] = fmaf(xv.x, w.x, acc[j]);
            acc[j] = fmaf(xv.y, w.y, acc[j]);
            acc[j] = fmaf(xv.z, w.z, acc[j]);
            acc[j] = fmaf(xv.w, w.w, acc[j]);
        }
    }

    // ---- 8 single-qubit circuits ----
    // Angles: x0 = pi*tanh(p0), x1 = pi*tanh(p1), identical across the 3 layers.
    // RZ applied as b *= e^{i*phi} (global phase dropped); final RZ skipped.
    float q[8];
    #pragma unroll
    for (int u = 0; u < 8; ++u) {
        float th0 = fast_tanh(acc[2 * u + 0]);
        float th1 = fast_tanh(acc[2 * u + 1]);
        float c  = __cosf(0.5f * PI_F * th0);   // cos(x0/2)
        float s  = __sinf(0.5f * PI_F * th0);
        float zr = __cosf(PI_F * th1);          // e^{i*x1}
        float zi = __sinf(PI_F * th1);

        float ar = c, ai = 0.0f, br = s, bi = 0.0f;  // layer 0 RY applied to |0>
        #pragma unroll
        for (int l = 0; l < 3; ++l) {
            if (l > 0) {  // RY(x0)
                float nar = c * ar - s * br, nai = c * ai - s * bi;
                float nbr = s * ar + c * br, nbi = s * ai + c * bi;
                ar = nar; ai = nai; br = nbr; bi = nbi;
            }
            // RZ(x1 + qw0): phase = (zr,zi)*(e0r,e0i)
            float e0r = rot_s[u][l][0], e0i = rot_s[u][l][1];
            float pr = zr * e0r - zi * e0i;
            float pq = zr * e0i + zi * e0r;
            float nbr = br * pr - bi * pq, nbi = br * pq + bi * pr;
            br = nbr; bi = nbi;
            // RY(qw1)
            float c1 = rot_s[u][l][2], s1 = rot_s[u][l][3];
            float tar = c1 * ar - s1 * br, tai = c1 * ai - s1 * bi;
            float tbr = s1 * ar + c1 * br, tbi = s1 * ai + c1 * bi;
            ar = tar; ai = tai; br = tbr; bi = tbi;
            // RZ(qw2) — phase-only at the last layer, skip then
            if (l < 2) {
                float e2r = rot_s[u][l][4], e2i = rot_s[u][l][5];
                float ubr = br * e2r - bi * e2i, ubi = br * e2i + bi * e2r;
                br = ubr; bi = ubi;
            }
        }
        q[u] = (ar * ar + ai * ai) - (br * br + bi * bi);
    }

    // ---- head: relu(q @ W1^T + b1) @ W2^T + b2 ----
    float ov[10];
    #pragma unroll
    for (int c2 = 0; c2 < 10; ++c2) ov[c2] = b2_s[c2];
    #pragma unroll
    for (int j = 0; j < 32; ++j) {
        float h = b1_s[j];
        #pragma unroll
        for (int u = 0; u < 8; ++u) h = fmaf(q[u], w1_s[j * 8 + u], h);
        h = fmaxf(h, 0.0f);
        #pragma unroll
        for (int c2 = 0; c2 < 10; ++c2) ov[c2] = fmaf(h, w2_s[c2 * 32 + j], ov[c2]);
    }

    // ---- stage output in LDS, write coalesced ----
    #pragma unroll
    for (int c2 = 0; c2 < 10; ++c2) out_s[t * 10 + c2] = ov[c2];
    __syncthreads();
    const int base = blockIdx.x * (TB * 10);
    #pragma unroll
    for (int k = 0; k < 10; ++k) {
        int idx = base + k * TB + t;
        if (idx < nrows * 10) out[idx] = out_s[k * TB + t];
    }
}

extern "C" void kernel_launch(void* const* d_in, const int* in_sizes, int n_in,
                              void* d_out, int out_size, void* d_ws, size_t ws_size,
                              hipStream_t stream) {
    const float* x  = (const float*)d_in[0];
    const float* Wp = (const float*)d_in[1];
    const float* bp = (const float*)d_in[2];
    const float* qw = (const float*)d_in[3];
    const float* W1 = (const float*)d_in[4];
    const float* b1 = (const float*)d_in[5];
    const float* W2 = (const float*)d_in[6];
    const float* b2 = (const float*)d_in[7];
    float* out = (float*)d_out;

    const int nrows = in_sizes[0] / 256;
    const int nblocks = (nrows + TB - 1) / TB;
    sqru_fused_kernel<<<nblocks, TB, 0, stream>>>(x, Wp, bp, qw, W1, b1, W2, b2, out, nrows);
}